// Round 6
// baseline (651.753 us; speedup 1.0000x reference)
//
#include <hip/hip_runtime.h>
#include <hip/hip_bf16.h>

#define SS 2048
#define HH 512

typedef __attribute__((ext_vector_type(8))) short short8;
typedef __attribute__((ext_vector_type(4))) float f32x4;

__device__ __forceinline__ float bflo(unsigned u) { return __uint_as_float(u << 16); }
__device__ __forceinline__ float bfhi(unsigned u) { return __uint_as_float(u & 0xffff0000u); }

__device__ __forceinline__ short f2bf(float v) {
  __hip_bfloat16 h = __float2bfloat16(v);
  return *reinterpret_cast<short*>(&h);
}

__device__ __forceinline__ float tanh_fast(float x) {
  x = fminf(fmaxf(x, -15.f), 15.f);
  float e = __expf(2.f * x);
  return 1.f - 2.f * __builtin_amdgcn_rcpf(e + 1.f);  // v_rcp_f32, no slow fdiv
}

// async global -> LDS, 16B per lane (dest = wave-uniform base + lane*16)
__device__ __forceinline__ void gll16(const void* g, void* l) {
  __builtin_amdgcn_global_load_lds(
      (const __attribute__((address_space(1))) unsigned int*)g,
      (__attribute__((address_space(3))) unsigned int*)l, 16, 0, 0);
}

// ---------------- prep: 0..63 W1 transpose; 64..319 qp partials; 320 flag/tmap/tickets ----------------
// Each block detects the dtype itself (wave-0 ballot over 64 strided samples of E)
// -> no k_detect launch, no dependency bubble.
__global__ __launch_bounds__(256) void k_prep(const unsigned* __restrict__ Eu,
                                              const int* __restrict__ lens,
                                              const __hip_bfloat16* __restrict__ W1b,
                                              const float* __restrict__ W1f,
                                              const __hip_bfloat16* __restrict__ qb,
                                              const float* __restrict__ qf,
                                              const __hip_bfloat16* __restrict__ W2b,
                                              const float* __restrict__ W2f,
                                              __hip_bfloat16* __restrict__ W1T,
                                              float* __restrict__ qp_part,
                                              int* __restrict__ flag,
                                              int* __restrict__ tmap,
                                              int* __restrict__ livep,
                                              int* __restrict__ cnt) {
  __shared__ int smode;
  __shared__ __hip_bfloat16 t[64][65];
  __shared__ float qs[128];
  const int tid = threadIdx.x;

  // ---- per-block dtype detect (wave 0) ----
  if (tid < 64) {
    unsigned w = Eu[(size_t)tid * 4097];
    unsigned e = (w >> 7) & 0xFF;  // exponent field of the low bf16 half
    bool inr = (e >= 90 && e <= 140);
    unsigned long long m = __ballot(inr);
    if (tid == 0) smode = (__popcll(m) >= 48) ? 1 : 0;
  }
  __syncthreads();
  const int mode = smode;

  if (blockIdx.x < 64) {
    // ---- W1 transpose tile: W1T[d][h] = W1[h][d] ----
    int r0 = (blockIdx.x >> 3) * 64, c0 = (blockIdx.x & 7) * 64;
    for (int i = tid; i < 4096; i += 256) {
      int r = i >> 6, c = i & 63;
      size_t idx = (size_t)(r0 + r) * HH + c0 + c;
      float v = mode ? (float)W1b[idx] : W1f[idx];
      t[r][c] = __float2bfloat16(v);
    }
    __syncthreads();
    for (int i = tid; i < 4096; i += 256) {
      int r = i >> 6, c = i & 63;
      W1T[(size_t)(c0 + r) * HH + r0 + c] = t[c][r];
    }
  } else if (blockIdx.x < 320) {
    // ---- qp_part[p][b][d] = sum_{h in part p} q[b][h] * W2[h][d] ----
    int bx = blockIdx.x - 64;
    int b = bx & 63, p = bx >> 6, h0 = p * 128;
    if (tid < 128) {
      size_t qi = (size_t)b * HH + h0 + tid;
      qs[tid] = mode ? (float)qb[qi] : qf[qi];
    }
    __syncthreads();
    int col = tid * 2;
    float a0 = 0.f, a1 = 0.f;
    if (mode) {
#pragma unroll 4
      for (int i = 0; i < 128; ++i) {
        float qa = qs[i];
        unsigned u = *(const unsigned*)(W2b + (size_t)(h0 + i) * HH + col);
        a0 = fmaf(qa, bflo(u), a0);
        a1 = fmaf(qa, bfhi(u), a1);
      }
    } else {
#pragma unroll 4
      for (int i = 0; i < 128; ++i) {
        float qa = qs[i];
        float2 v = *(const float2*)(W2f + (size_t)(h0 + i) * HH + col);
        a0 = fmaf(qa, v.x, a0);
        a1 = fmaf(qa, v.y, a1);
      }
    }
    float* dst = qp_part + ((size_t)p * 64 + b) * HH + col;
    dst[0] = a0;
    dst[1] = a1;
  } else {
    // ---- block 320: flag, live 64-row tile map, ticket counters (wave 0 only) ----
    if (tid < 64) {
      if (tid == 0) *flag = mode;
      int len = lens[tid];
      int n = (len + 63) >> 6;  // 1..32 tiles of 64 rows
      int off = n;
#pragma unroll
      for (int o = 1; o < 64; o <<= 1) {
        int v = __shfl_up(off, o);
        if (tid >= o) off += v;
      }
      int base = off - n;
      for (int j = 0; j < n; ++j) tmap[base + j] = tid * 32 + j;
      if (tid == 63) *livep = off;
      cnt[tid] = 0;
    }
  }
}

// ---------------- fused energy + tile softmax + PV partial + ticketed batch reduce ----------------
// 64-row tiles, compacted live map. Each wave owns 16 rows (afr[16] = 64 VGPRs);
// launch_bounds(256,3) => 3 blocks/CU. B staged via global_load_lds into a 4-deep
// LDS ring (pre-swizzled GLOBAL source + linear LDS dest + swizzled ds_read);
// counted `s_waitcnt vmcnt(4)` + raw s_barrier per step (never drained in-loop).
// After the tile's tpart write: device-scope ticket on cnt[b]; the LAST tile-block
// of each batch acquire-fences and does the <=32-tile softmax combine + store
// (replaces the k_reduce launch; G16: agent-scope RMW + fences for cross-XCD).
__global__ __launch_bounds__(256, 3) void k_energy(
    const __hip_bfloat16* __restrict__ Eb, const float* __restrict__ Ef,
    const __hip_bfloat16* __restrict__ W1T, const float* __restrict__ qpp,
    const __hip_bfloat16* __restrict__ Vwb, const float* __restrict__ Vwf,
    const int* __restrict__ flagp, const int* __restrict__ lens,
    const int* __restrict__ tmap, const int* __restrict__ livep,
    float* __restrict__ tpart, int* __restrict__ cnt,
    __hip_bfloat16* __restrict__ outb, float* __restrict__ outf) {
  __shared__ __align__(16) __hip_bfloat16 Bt[4][128 * 32];  // 4 x 8 KB ring
  __shared__ float qps[HH];
  __shared__ float Vs[HH];
  __shared__ float p[64];
  __shared__ float red[4];
  __shared__ f32x4 part[128];
  __shared__ int swin;

  const int tid = threadIdx.x;
  const int wave = tid >> 6, lane = tid & 63;
  const int quad = lane >> 4, l16 = lane & 15;
  const int live = *livep;
  if (blockIdx.x >= live) return;  // block-uniform, before any barrier
  const int mode = *flagp;

  const int tile = tmap[blockIdx.x];
  const int b = tile >> 5;
  const int srow = (tile & 31) * 64;
  const int row0 = b * SS + srow;
  const int len = lens[b];
  const int nch = (len + 63) >> 6;

  // ---- B staging lane mapping (16B chunk per lane; swizzle folded into global addr) ----
  const int rs0 = wave * 32 + (lane >> 2);
  const int rs1 = rs0 + 16;
  const int kg0 = ((lane & 3) - (rs0 >> 1)) & 3;
  const int kg1 = ((lane & 3) - (rs1 >> 1)) & 3;
  const __hip_bfloat16* pb0 = W1T + (size_t)rs0 * HH + kg0 * 8;
  const __hip_bfloat16* pb1 = W1T + (size_t)rs1 * HH + kg1 * 8;
  char* ldsB = (char*)&Bt[0][0];
  char* ldW = ldsB + wave * 2048;  // wave-uniform LDS dest base (lane*16 added by HW)

  // fragment read offsets: B[k=quad*8+j][n = cb*16 + l16] (XOR-swizzled slot)
  int offB[8];
#pragma unroll
  for (int cb = 0; cb < 8; ++cb) {
    int n = cb * 16 + l16;
    offB[cb] = n * 32 + (((quad + (n >> 1)) & 3) << 3);
  }

  // ---- prologue: issue ring slots 0..2 (6 async loads in flight) ----
#pragma unroll
  for (int s = 0; s < 3; ++s) {
    int o = s << 5;
    gll16(pb0 + o, ldW + s * 8192);
    gll16(pb1 + o, ldW + s * 8192 + 1024);
  }

  // ---- A fragments -> registers ----
  // afr[kt]: A[m = wave*16 + l16][k = kt*32 + quad*8 + j]
  short8 afr[16];
  {
    const size_t eBase = (size_t)(row0 + wave * 16 + l16) * HH + quad * 8;
    if (mode) {
      const __hip_bfloat16* pa = Eb + eBase;
#pragma unroll
      for (int kt = 0; kt < 16; ++kt) afr[kt] = *(const short8*)(pa + kt * 32);
    } else {
      const float* pa = Ef + eBase;
#pragma unroll
      for (int g = 0; g < 4; ++g) {
        f32x4 x0[4], x1[4];
#pragma unroll
        for (int k = 0; k < 4; ++k) {
          const float* pp = pa + (g * 4 + k) * 32;
          x0[k] = *(const f32x4*)pp;
          x1[k] = *(const f32x4*)(pp + 4);
        }
#pragma unroll
        for (int k = 0; k < 4; ++k) {
          short8 v;
#pragma unroll
          for (int j = 0; j < 4; ++j) {
            v[j] = f2bf(x0[k][j]);
            v[j + 4] = f2bf(x1[k][j]);
          }
          afr[g * 4 + k] = v;
        }
      }
    }
  }

  // ---- qps / Vs staging ----
  for (int i = tid; i < HH; i += 256) {
    qps[i] = qpp[(size_t)b * HH + i] + qpp[(size_t)(64 + b) * HH + i] +
             qpp[(size_t)(128 + b) * HH + i] + qpp[(size_t)(192 + b) * HH + i];
    Vs[i] = mode ? (float)Vwb[i] : Vwf[i];
  }

  float eacc[4] = {0.f, 0.f, 0.f, 0.f};

  for (int nc = 0; nc < 4; ++nc) {
    f32x4 acc[8];
#pragma unroll
    for (int cb = 0; cb < 8; ++cb) acc[cb] = (f32x4){0.f, 0.f, 0.f, 0.f};

#pragma unroll
    for (int kt = 0; kt < 16; ++kt) {
      // pin previous step's MFMAs above the barrier, wait own slot-t loads, sync
      __builtin_amdgcn_sched_barrier(0);
      asm volatile("s_waitcnt vmcnt(4)" ::: "memory");
      __builtin_amdgcn_s_barrier();
      __builtin_amdgcn_sched_barrier(0);

      // issue prefetch for step t+3 into ring slot (kt+3)&3 (clamped at tail)
      {
        int t2 = nc * 16 + kt + 3;
        if (t2 > 63) t2 = 63;
        int o = ((t2 >> 4) << 16) + ((t2 & 15) << 5);
        char* ld = ldW + ((kt + 3) & 3) * 8192;
        gll16(pb0 + o, ld);
        gll16(pb1 + o, ld + 1024);
      }

      // compute step t from ring slot kt&3
      const __hip_bfloat16* bb = &Bt[kt & 3][0];
      short8 af = afr[kt];
#pragma unroll
      for (int cb = 0; cb < 8; ++cb) {
        short8 bf = *(const short8*)(bb + offB[cb]);
        acc[cb] = __builtin_amdgcn_mfma_f32_16x16x32_bf16(af, bf, acc[cb], 0, 0, 0);
      }
    }

    // epilogue (overlaps in-flight prefetches): +qp, tanh, dot V (C/D: col=l16, row=quad*4+r)
#pragma unroll
    for (int cb = 0; cb < 8; ++cb) {
      int col = nc * 128 + cb * 16 + l16;
      float qv = qps[col], vv = Vs[col];
#pragma unroll
      for (int r = 0; r < 4; ++r) {
        float tv = tanh_fast(acc[cb][r] + qv);
        eacc[r] = fmaf(vv, tv, eacc[r]);
      }
    }
  }

  // ---- energies -> LDS p[64] (masked rows -inf) ----
#pragma unroll
  for (int r = 0; r < 4; ++r) {
    float v = eacc[r];
#pragma unroll
    for (int o = 1; o < 16; o <<= 1) v += __shfl_xor(v, o);
    if (l16 == 0) {
      int row = wave * 16 + quad * 4 + r;
      p[row] = (srow + row < len) ? v : -3.0e38f;
    }
  }
  __syncthreads();  // full vmcnt(0)+lgkm drain: also retires tail prefetch junk

  // ---- tile softmax (wave 0): m_t, d_t, weights -> p[] ----
  if (wave == 0) {
    float e = p[lane];
    float m = e;
#pragma unroll
    for (int o = 1; o < 64; o <<= 1) m = fmaxf(m, __shfl_xor(m, o));
    float w = __expf(e - m);
    float d = w;
#pragma unroll
    for (int o = 1; o < 64; o <<= 1) d += __shfl_xor(d, o);
    p[lane] = w;
    if (lane == 0) {
      red[0] = m;
      red[1] = d;
    }
  }
  __syncthreads();
  const float m_t = red[0], d_t = red[1];

  // ---- PV partial: ctx_part[h] = sum_{s in tile} w_s * E[s][h] (E slab cache-hot) ----
  const int n = min(64, len - srow);
  const int h0 = (tid & 127) * 4;
  const int rr = tid >> 7;  // 0/1: waves {0,1} even rows, {2,3} odd
  f32x4 a = {0.f, 0.f, 0.f, 0.f};
  if (mode) {
    const __hip_bfloat16* base = Eb + (size_t)row0 * HH + h0;
#pragma unroll 8
    for (int i = rr; i < n; i += 2) {
      float wv = p[i];
      uint2 u = *(const uint2*)(base + (size_t)i * HH);
      a[0] = fmaf(wv, bflo(u.x), a[0]);
      a[1] = fmaf(wv, bfhi(u.x), a[1]);
      a[2] = fmaf(wv, bflo(u.y), a[2]);
      a[3] = fmaf(wv, bfhi(u.y), a[3]);
    }
  } else {
    const float* base = Ef + (size_t)row0 * HH + h0;
#pragma unroll 8
    for (int i = rr; i < n; i += 2) {
      float wv = p[i];
      f32x4 v = *(const f32x4*)(base + (size_t)i * HH);
      a[0] = fmaf(wv, v[0], a[0]);
      a[1] = fmaf(wv, v[1], a[1]);
      a[2] = fmaf(wv, v[2], a[2]);
      a[3] = fmaf(wv, v[3], a[3]);
    }
  }
  if (tid >= 128) part[tid - 128] = a;
  __syncthreads();
  if (tid < 128) {
    f32x4 o = part[tid];
    f32x4 s;
    s[0] = a[0] + o[0];
    s[1] = a[1] + o[1];
    s[2] = a[2] + o[2];
    s[3] = a[3] + o[3];
    *(f32x4*)(tpart + (size_t)tile * 516 + h0) = s;
  }
  if (tid == 0) {
    tpart[(size_t)tile * 516 + 512] = m_t;
    tpart[(size_t)tile * 516 + 513] = d_t;
  }

  // ---- ticket: last tile-block of batch b combines the partials + stores ----
  __threadfence();   // release our tpart writes to device scope (after syncthreads below)
  __syncthreads();   // all threads' stores + fences done
  if (tid == 0) {
    int r = __hip_atomic_fetch_add(&cnt[b], 1, __ATOMIC_ACQ_REL, __HIP_MEMORY_SCOPE_AGENT);
    swin = (r == nch - 1) ? 1 : 0;
  }
  __syncthreads();
  if (!swin) return;  // block-uniform; no barriers past this point

  __threadfence();  // acquire: read other tiles' tpart fresh (cross-XCD)
  const float* tb = tpart + (size_t)b * 32 * 516;
  float mm = -3.0e38f;
  for (int c = 0; c < nch; ++c) mm = fmaxf(mm, tb[c * 516 + 512]);
  const int h = tid * 2;
  float den = 0.f, a0 = 0.f, a1 = 0.f;
  for (int c = 0; c < nch; ++c) {
    float sc = __expf(tb[c * 516 + 512] - mm);
    den = fmaf(tb[c * 516 + 513], sc, den);
    float2 v = *(const float2*)(tb + c * 516 + h);
    a0 = fmaf(sc, v.x, a0);
    a1 = fmaf(sc, v.y, a1);
  }
  float inv = 1.f / den;
  int i = b * HH + h;
  if (mode) {
    outb[i] = __float2bfloat16(a0 * inv);
    outb[i + 1] = __float2bfloat16(a1 * inv);
  } else {
    outf[i] = a0 * inv;
    outf[i + 1] = a1 * inv;
  }
}

extern "C" void kernel_launch(void* const* d_in, const int* in_sizes, int n_in,
                              void* d_out, int out_size, void* d_ws, size_t ws_size,
                              hipStream_t stream) {
  const __hip_bfloat16* qb  = (const __hip_bfloat16*)d_in[0];
  const float*          qf  = (const float*)d_in[0];
  const __hip_bfloat16* Eb  = (const __hip_bfloat16*)d_in[1];
  const float*          Ef  = (const float*)d_in[1];
  const int* lens           = (const int*)d_in[2];
  const __hip_bfloat16* W1b = (const __hip_bfloat16*)d_in[3];
  const float*          W1f = (const float*)d_in[3];
  const __hip_bfloat16* W2b = (const __hip_bfloat16*)d_in[4];
  const float*          W2f = (const float*)d_in[4];
  const __hip_bfloat16* Vwb = (const __hip_bfloat16*)d_in[5];
  const float*          Vwf = (const float*)d_in[5];
  __hip_bfloat16* outb      = (__hip_bfloat16*)d_out;
  float*          outf      = (float*)d_out;

  char* ws = (char*)d_ws;
  __hip_bfloat16* W1T = (__hip_bfloat16*)(ws);           // 512 KB @ 0
  float* qp_part      = (float*)(ws + 524288);           // 512 KB: [4][64][512]
  float* tpart        = (float*)(ws + 1048576);          // 4.23 MB: [2048][516]
  int* flag           = (int*)(ws + 5275648);            // 4 B
  int* tmap           = (int*)(ws + 5275652);            // 8 KB: live tile ids
  int* livep          = (int*)(ws + 5283844);            // 4 B
  int* cnt            = (int*)(ws + 5283848);            // 256 B: per-batch tickets

  k_prep<<<dim3(321), 256, 0, stream>>>((const unsigned*)d_in[1], lens, W1b, W1f, qb, qf,
                                        W2b, W2f, W1T, qp_part, flag, tmap, livep, cnt);
  k_energy<<<dim3(2048), 256, 0, stream>>>(Eb, Ef, W1T, qp_part, Vwb, Vwf, flag, lens,
                                           tmap, livep, tpart, cnt, outb, outf);
}

// Round 8
// 442.990 us; speedup vs baseline: 1.4713x; 1.4713x over previous
//
#include <hip/hip_runtime.h>
#include <hip/hip_bf16.h>

#define SS 2048
#define HH 512

typedef __attribute__((ext_vector_type(8))) short short8;
typedef __attribute__((ext_vector_type(4))) float f32x4;

__device__ __forceinline__ float bflo(unsigned u) { return __uint_as_float(u << 16); }
__device__ __forceinline__ float bfhi(unsigned u) { return __uint_as_float(u & 0xffff0000u); }

__device__ __forceinline__ short f2bf(float v) {
  __hip_bfloat16 h = __float2bfloat16(v);
  return *reinterpret_cast<short*>(&h);
}

__device__ __forceinline__ float tanh_fast(float x) {
  x = fminf(fmaxf(x, -15.f), 15.f);
  float e = __expf(2.f * x);
  return 1.f - 2.f * __builtin_amdgcn_rcpf(e + 1.f);  // v_rcp_f32, no slow fdiv
}

// async global -> LDS, 16B per lane (dest = wave-uniform base + lane*16)
__device__ __forceinline__ void gll16(const void* g, void* l) {
  __builtin_amdgcn_global_load_lds(
      (const __attribute__((address_space(1))) unsigned int*)g,
      (__attribute__((address_space(3))) unsigned int*)l, 16, 0, 0);
}

// ---------------- prep: 0..63 W1 transpose; 64..319 qp partials; 320 flag/tmap ----------------
// Each block detects the dtype itself (wave-0 ballot over 64 strided samples of E)
// -> no k_detect launch, no dependency bubble. NO cross-block fencing anywhere
// (round-6 lesson: device-scope fences in-kernel cost ~200us; a launch costs ~5).
__global__ __launch_bounds__(256) void k_prep(const unsigned* __restrict__ Eu,
                                              const int* __restrict__ lens,
                                              const __hip_bfloat16* __restrict__ W1b,
                                              const float* __restrict__ W1f,
                                              const __hip_bfloat16* __restrict__ qb,
                                              const float* __restrict__ qf,
                                              const __hip_bfloat16* __restrict__ W2b,
                                              const float* __restrict__ W2f,
                                              __hip_bfloat16* __restrict__ W1T,
                                              float* __restrict__ qp_part,
                                              int* __restrict__ flag,
                                              int* __restrict__ tmap,
                                              int* __restrict__ livep) {
  __shared__ int smode;
  __shared__ __hip_bfloat16 t[64][65];
  __shared__ float qs[128];
  const int tid = threadIdx.x;

  // ---- per-block dtype detect (wave 0) ----
  if (tid < 64) {
    unsigned w = Eu[(size_t)tid * 4097];
    unsigned e = (w >> 7) & 0xFF;  // exponent field of the low bf16 half
    bool inr = (e >= 90 && e <= 140);
    unsigned long long m = __ballot(inr);
    if (tid == 0) smode = (__popcll(m) >= 48) ? 1 : 0;
  }
  __syncthreads();
  const int mode = smode;

  if (blockIdx.x < 64) {
    // ---- W1 transpose tile: W1T[d][h] = W1[h][d] ----
    int r0 = (blockIdx.x >> 3) * 64, c0 = (blockIdx.x & 7) * 64;
    for (int i = tid; i < 4096; i += 256) {
      int r = i >> 6, c = i & 63;
      size_t idx = (size_t)(r0 + r) * HH + c0 + c;
      float v = mode ? (float)W1b[idx] : W1f[idx];
      t[r][c] = __float2bfloat16(v);
    }
    __syncthreads();
    for (int i = tid; i < 4096; i += 256) {
      int r = i >> 6, c = i & 63;
      W1T[(size_t)(c0 + r) * HH + r0 + c] = t[c][r];
    }
  } else if (blockIdx.x < 320) {
    // ---- qp_part[p][b][d] = sum_{h in part p} q[b][h] * W2[h][d] ----
    int bx = blockIdx.x - 64;
    int b = bx & 63, p = bx >> 6, h0 = p * 128;
    if (tid < 128) {
      size_t qi = (size_t)b * HH + h0 + tid;
      qs[tid] = mode ? (float)qb[qi] : qf[qi];
    }
    __syncthreads();
    int col = tid * 2;
    float a0 = 0.f, a1 = 0.f;
    if (mode) {
#pragma unroll 4
      for (int i = 0; i < 128; ++i) {
        float qa = qs[i];
        unsigned u = *(const unsigned*)(W2b + (size_t)(h0 + i) * HH + col);
        a0 = fmaf(qa, bflo(u), a0);
        a1 = fmaf(qa, bfhi(u), a1);
      }
    } else {
#pragma unroll 4
      for (int i = 0; i < 128; ++i) {
        float qa = qs[i];
        float2 v = *(const float2*)(W2f + (size_t)(h0 + i) * HH + col);
        a0 = fmaf(qa, v.x, a0);
        a1 = fmaf(qa, v.y, a1);
      }
    }
    float* dst = qp_part + ((size_t)p * 64 + b) * HH + col;
    dst[0] = a0;
    dst[1] = a1;
  } else {
    // ---- block 320: flag + live 64-row tile map (wave 0 only) ----
    if (tid < 64) {
      if (tid == 0) *flag = mode;
      int len = lens[tid];
      int n = (len + 63) >> 6;  // 1..32 tiles of 64 rows
      int off = n;
#pragma unroll
      for (int o = 1; o < 64; o <<= 1) {
        int v = __shfl_up(off, o);
        if (tid >= o) off += v;
      }
      int base = off - n;
      for (int j = 0; j < n; ++j) tmap[base + j] = tid * 32 + j;
      if (tid == 63) *livep = off;
    }
  }
}

// ---------------- fused energy + tile softmax + PV partial, 64-row tiles ----------------
// (verbatim round-5 kernel: best verified, k_energy < 158us, no spills)
// Grid 2048, compacted live tiles (tmap). Each wave owns 16 rows (afr[16] = 64 VGPRs);
// launch_bounds(256,3) => 3 blocks/CU. B staged via global_load_lds into a 4-deep
// LDS ring (pre-swizzled GLOBAL source + linear LDS dest + swizzled ds_read);
// counted `s_waitcnt vmcnt(4)` + raw s_barrier per step (never drained in-loop).
__global__ __launch_bounds__(256, 3) void k_energy(
    const __hip_bfloat16* __restrict__ Eb, const float* __restrict__ Ef,
    const __hip_bfloat16* __restrict__ W1T, const float* __restrict__ qpp,
    const __hip_bfloat16* __restrict__ Vwb, const float* __restrict__ Vwf,
    const int* __restrict__ flagp, const int* __restrict__ lens,
    const int* __restrict__ tmap, const int* __restrict__ livep,
    float* __restrict__ tpart) {
  __shared__ __align__(16) __hip_bfloat16 Bt[4][128 * 32];  // 4 x 8 KB ring
  __shared__ float qps[HH];
  __shared__ float Vs[HH];
  __shared__ float p[64];
  __shared__ float red[4];
  __shared__ f32x4 part[128];

  const int tid = threadIdx.x;
  const int wave = tid >> 6, lane = tid & 63;
  const int quad = lane >> 4, l16 = lane & 15;
  const int live = *livep;
  if (blockIdx.x >= live) return;  // block-uniform, before any barrier
  const int mode = *flagp;

  const int tile = tmap[blockIdx.x];
  const int b = tile >> 5;
  const int srow = (tile & 31) * 64;
  const int row0 = b * SS + srow;
  const int len = lens[b];

  // ---- B staging lane mapping (16B chunk per lane; swizzle folded into global addr) ----
  const int rs0 = wave * 32 + (lane >> 2);
  const int rs1 = rs0 + 16;
  const int kg0 = ((lane & 3) - (rs0 >> 1)) & 3;
  const int kg1 = ((lane & 3) - (rs1 >> 1)) & 3;
  const __hip_bfloat16* pb0 = W1T + (size_t)rs0 * HH + kg0 * 8;
  const __hip_bfloat16* pb1 = W1T + (size_t)rs1 * HH + kg1 * 8;
  char* ldsB = (char*)&Bt[0][0];
  char* ldW = ldsB + wave * 2048;  // wave-uniform LDS dest base (lane*16 added by HW)

  // fragment read offsets: B[k=quad*8+j][n = cb*16 + l16] (XOR-swizzled slot)
  int offB[8];
#pragma unroll
  for (int cb = 0; cb < 8; ++cb) {
    int n = cb * 16 + l16;
    offB[cb] = n * 32 + (((quad + (n >> 1)) & 3) << 3);
  }

  // ---- prologue: issue ring slots 0..2 (6 async loads in flight) ----
#pragma unroll
  for (int s = 0; s < 3; ++s) {
    int o = s << 5;
    gll16(pb0 + o, ldW + s * 8192);
    gll16(pb1 + o, ldW + s * 8192 + 1024);
  }

  // ---- A fragments -> registers ----
  // afr[kt]: A[m = wave*16 + l16][k = kt*32 + quad*8 + j]
  short8 afr[16];
  {
    const size_t eBase = (size_t)(row0 + wave * 16 + l16) * HH + quad * 8;
    if (mode) {
      const __hip_bfloat16* pa = Eb + eBase;
#pragma unroll
      for (int kt = 0; kt < 16; ++kt) afr[kt] = *(const short8*)(pa + kt * 32);
    } else {
      const float* pa = Ef + eBase;
#pragma unroll
      for (int g = 0; g < 4; ++g) {
        f32x4 x0[4], x1[4];
#pragma unroll
        for (int k = 0; k < 4; ++k) {
          const float* pp = pa + (g * 4 + k) * 32;
          x0[k] = *(const f32x4*)pp;
          x1[k] = *(const f32x4*)(pp + 4);
        }
#pragma unroll
        for (int k = 0; k < 4; ++k) {
          short8 v;
#pragma unroll
          for (int j = 0; j < 4; ++j) {
            v[j] = f2bf(x0[k][j]);
            v[j + 4] = f2bf(x1[k][j]);
          }
          afr[g * 4 + k] = v;
        }
      }
    }
  }

  // ---- qps / Vs staging ----
  for (int i = tid; i < HH; i += 256) {
    qps[i] = qpp[(size_t)b * HH + i] + qpp[(size_t)(64 + b) * HH + i] +
             qpp[(size_t)(128 + b) * HH + i] + qpp[(size_t)(192 + b) * HH + i];
    Vs[i] = mode ? (float)Vwb[i] : Vwf[i];
  }

  float eacc[4] = {0.f, 0.f, 0.f, 0.f};

  for (int nc = 0; nc < 4; ++nc) {
    f32x4 acc[8];
#pragma unroll
    for (int cb = 0; cb < 8; ++cb) acc[cb] = (f32x4){0.f, 0.f, 0.f, 0.f};

#pragma unroll
    for (int kt = 0; kt < 16; ++kt) {
      // pin previous step's MFMAs above the barrier, wait own slot-t loads, sync
      __builtin_amdgcn_sched_barrier(0);
      asm volatile("s_waitcnt vmcnt(4)" ::: "memory");
      __builtin_amdgcn_s_barrier();
      __builtin_amdgcn_sched_barrier(0);

      // issue prefetch for step t+3 into ring slot (kt+3)&3 (clamped at tail)
      {
        int t2 = nc * 16 + kt + 3;
        if (t2 > 63) t2 = 63;
        int o = ((t2 >> 4) << 16) + ((t2 & 15) << 5);
        char* ld = ldW + ((kt + 3) & 3) * 8192;
        gll16(pb0 + o, ld);
        gll16(pb1 + o, ld + 1024);
      }

      // compute step t from ring slot kt&3
      const __hip_bfloat16* bb = &Bt[kt & 3][0];
      short8 af = afr[kt];
#pragma unroll
      for (int cb = 0; cb < 8; ++cb) {
        short8 bf = *(const short8*)(bb + offB[cb]);
        acc[cb] = __builtin_amdgcn_mfma_f32_16x16x32_bf16(af, bf, acc[cb], 0, 0, 0);
      }
    }

    // epilogue (overlaps in-flight prefetches): +qp, tanh, dot V (C/D: col=l16, row=quad*4+r)
#pragma unroll
    for (int cb = 0; cb < 8; ++cb) {
      int col = nc * 128 + cb * 16 + l16;
      float qv = qps[col], vv = Vs[col];
#pragma unroll
      for (int r = 0; r < 4; ++r) {
        float tv = tanh_fast(acc[cb][r] + qv);
        eacc[r] = fmaf(vv, tv, eacc[r]);
      }
    }
  }

  // ---- energies -> LDS p[64] (masked rows -inf) ----
#pragma unroll
  for (int r = 0; r < 4; ++r) {
    float v = eacc[r];
#pragma unroll
    for (int o = 1; o < 16; o <<= 1) v += __shfl_xor(v, o);
    if (l16 == 0) {
      int row = wave * 16 + quad * 4 + r;
      p[row] = (srow + row < len) ? v : -3.0e38f;
    }
  }
  __syncthreads();  // full vmcnt(0)+lgkm drain: also retires tail prefetch junk

  // ---- tile softmax (wave 0): m_t, d_t, weights -> p[] ----
  if (wave == 0) {
    float e = p[lane];
    float m = e;
#pragma unroll
    for (int o = 1; o < 64; o <<= 1) m = fmaxf(m, __shfl_xor(m, o));
    float w = __expf(e - m);
    float d = w;
#pragma unroll
    for (int o = 1; o < 64; o <<= 1) d += __shfl_xor(d, o);
    p[lane] = w;
    if (lane == 0) {
      red[0] = m;
      red[1] = d;
    }
  }
  __syncthreads();
  const float m_t = red[0], d_t = red[1];

  // ---- PV partial: ctx_part[h] = sum_{s in tile} w_s * E[s][h] (E slab cache-hot) ----
  const int n = min(64, len - srow);
  const int h0 = (tid & 127) * 4;
  const int rr = tid >> 7;  // 0/1: waves {0,1} even rows, {2,3} odd
  f32x4 a = {0.f, 0.f, 0.f, 0.f};
  if (mode) {
    const __hip_bfloat16* base = Eb + (size_t)row0 * HH + h0;
#pragma unroll 8
    for (int i = rr; i < n; i += 2) {
      float wv = p[i];
      uint2 u = *(const uint2*)(base + (size_t)i * HH);
      a[0] = fmaf(wv, bflo(u.x), a[0]);
      a[1] = fmaf(wv, bfhi(u.x), a[1]);
      a[2] = fmaf(wv, bflo(u.y), a[2]);
      a[3] = fmaf(wv, bfhi(u.y), a[3]);
    }
  } else {
    const float* base = Ef + (size_t)row0 * HH + h0;
#pragma unroll 8
    for (int i = rr; i < n; i += 2) {
      float wv = p[i];
      f32x4 v = *(const f32x4*)(base + (size_t)i * HH);
      a[0] = fmaf(wv, v[0], a[0]);
      a[1] = fmaf(wv, v[1], a[1]);
      a[2] = fmaf(wv, v[2], a[2]);
      a[3] = fmaf(wv, v[3], a[3]);
    }
  }
  if (tid >= 128) part[tid - 128] = a;
  __syncthreads();
  if (tid < 128) {
    f32x4 o = part[tid];
    f32x4 s;
    s[0] = a[0] + o[0];
    s[1] = a[1] + o[1];
    s[2] = a[2] + o[2];
    s[3] = a[3] + o[3];
    *(f32x4*)(tpart + (size_t)tile * 516 + h0) = s;
  }
  if (tid == 0) {
    tpart[(size_t)tile * 516 + 512] = m_t;
    tpart[(size_t)tile * 516 + 513] = d_t;
  }
}

// ---------------- per-batch reduce of tile partials + store ----------------
__global__ __launch_bounds__(256) void k_reduce(const float* __restrict__ tpart,
                                                const int* __restrict__ lens,
                                                const int* __restrict__ flagp,
                                                __hip_bfloat16* __restrict__ outb,
                                                float* __restrict__ outf) {
  const int b = blockIdx.x, tid = threadIdx.x;
  const int nch = (lens[b] + 63) >> 6;  // only tiles k_energy actually wrote
  const float* tb = tpart + (size_t)b * 32 * 516;
  float m = -3.0e38f;
  for (int c = 0; c < nch; ++c) m = fmaxf(m, tb[c * 516 + 512]);
  const int h = tid * 2;
  float den = 0.f, a0 = 0.f, a1 = 0.f;
  for (int c = 0; c < nch; ++c) {
    float sc = __expf(tb[c * 516 + 512] - m);
    den = fmaf(tb[c * 516 + 513], sc, den);
    float2 v = *(const float2*)(tb + c * 516 + h);
    a0 = fmaf(sc, v.x, a0);
    a1 = fmaf(sc, v.y, a1);
  }
  float inv = 1.f / den;
  int i = b * HH + h;
  if (*flagp) {
    outb[i] = __float2bfloat16(a0 * inv);
    outb[i + 1] = __float2bfloat16(a1 * inv);
  } else {
    outf[i] = a0 * inv;
    outf[i + 1] = a1 * inv;
  }
}

extern "C" void kernel_launch(void* const* d_in, const int* in_sizes, int n_in,
                              void* d_out, int out_size, void* d_ws, size_t ws_size,
                              hipStream_t stream) {
  const __hip_bfloat16* qb  = (const __hip_bfloat16*)d_in[0];
  const float*          qf  = (const float*)d_in[0];
  const __hip_bfloat16* Eb  = (const __hip_bfloat16*)d_in[1];
  const float*          Ef  = (const float*)d_in[1];
  const int* lens           = (const int*)d_in[2];
  const __hip_bfloat16* W1b = (const __hip_bfloat16*)d_in[3];
  const float*          W1f = (const float*)d_in[3];
  const __hip_bfloat16* W2b = (const __hip_bfloat16*)d_in[4];
  const float*          W2f = (const float*)d_in[4];
  const __hip_bfloat16* Vwb = (const __hip_bfloat16*)d_in[5];
  const float*          Vwf = (const float*)d_in[5];
  __hip_bfloat16* outb      = (__hip_bfloat16*)d_out;
  float*          outf      = (float*)d_out;

  char* ws = (char*)d_ws;
  __hip_bfloat16* W1T = (__hip_bfloat16*)(ws);           // 512 KB @ 0
  float* qp_part      = (float*)(ws + 524288);           // 512 KB: [4][64][512]
  float* tpart        = (float*)(ws + 1048576);          // 4.23 MB: [2048][516]
  int* flag           = (int*)(ws + 5275648);            // 4 B
  int* tmap           = (int*)(ws + 5275652);            // 8 KB: live tile ids
  int* livep          = (int*)(ws + 5283844);            // 4 B

  k_prep<<<dim3(321), 256, 0, stream>>>((const unsigned*)d_in[1], lens, W1b, W1f, qb, qf,
                                        W2b, W2f, W1T, qp_part, flag, tmap, livep);
  k_energy<<<dim3(2048), 256, 0, stream>>>(Eb, Ef, W1T, qp_part, Vwb, Vwf, flag, lens,
                                           tmap, livep, tpart);
  k_reduce<<<dim3(64), 256, 0, stream>>>(tpart, lens, flag, outb, outf);
}